// Round 2
// baseline (1066.621 us; speedup 1.0000x reference)
//
#include <hip/hip_runtime.h>

// n=2048 rows, f=32 features. Output row r = [emb[i] (32) | emb[j] (32) | sw[j]],
// i = r>>11, j = r&2047. Output 2048*2048*65 f32 = 1.09 GB -> write-BW bound.
//
// v3: barrier-free wave-synchronous staging.
//  - Each WAVE owns a private 16x65-float LDS image (4160 B). No __syncthreads
//    anywhere -> the compiler never emits s_waitcnt vmcnt(0); global stores
//    stream continuously like the 6.26 TB/s fill kernel.
//  - Block = 256 thr (4 waves), 16,640 B LDS -> 8 blocks/CU = 32 waves/CU.
//  - Block b owns 16 consecutive 64-row tiles; i = const per block. Wave w
//    handles rows 16w..16w+15 of each tile (j-span = contiguous 2 KB of emb).
//  - Per tile per wave: prefetch next J-strip (2x global_load_dwordx4 + 1 sw),
//    ds_read_b128 x5 drain of current image, lgkmcnt fence, stores, scalar
//    ds_write of next J-strip. Cross-lane LDS WAR ordering pinned by explicit
//    lgkmcnt(0) + sched_barrier(0) (free: read data gates the stores anyway).
//  - emb[i] prefix (cols 0..31) written once per block, never rewritten.

#define NROWS 2048
#define ROWF 65
#define CHUNK_ROWS 16
#define CHUNK_FLOATS (CHUNK_ROWS * ROWF)   // 1040 floats = 4160 B per wave
#define CHUNK_F4 (CHUNK_FLOATS / 4)        // 260 float4
#define TILES_PER_BLOCK 16
#define NBLOCKS ((NROWS * NROWS / 64) / TILES_PER_BLOCK)  // 4096

__global__ __launch_bounds__(256) void expand_wavesync(
    const float* __restrict__ emb,   // [2048*32]
    const float* __restrict__ sw,    // [2048]
    float4* __restrict__ out)        // flat output as float4
{
    __shared__ __align__(16) float lds[4][CHUNK_FLOATS];  // 16,640 B

    const unsigned tid  = threadIdx.x;
    const unsigned w    = tid >> 6;
    const unsigned lane = tid & 63u;
    const unsigned t0   = blockIdx.x * TILES_PER_BLOCK;
    const unsigned i    = t0 >> 5;               // constant per block
    const unsigned rb   = w * CHUNK_ROWS;        // this wave's rows in a tile

    float* __restrict__ my = lds[w];

    // Fixed per-lane fill mapping: lane covers f4 #lane and #(lane+64) of the
    // 128-f4 (16x32) strip: row = q>>3, col = 4*(q&7).
    const unsigned jrA = lane >> 3;          // 0..7
    const unsigned jrB = jrA + 8u;           // 8..15
    const unsigned cc  = (lane & 7u) * 4u;   // 0,4,...,28

    // ---- I-part: cols 0..31 of all 16 rows, written once (scalar b32:
    // row stride 65 floats => float4 LDS writes would be misaligned). ----
    {
        const float4 vi = *(const float4*)(emb + i * 32u + cc);
        float* dA = my + jrA * ROWF + cc;
        float* dB = my + jrB * ROWF + cc;
        dA[0] = vi.x; dA[1] = vi.y; dA[2] = vi.z; dA[3] = vi.w;
        dB[0] = vi.x; dB[1] = vi.y; dB[2] = vi.z; dB[3] = vi.w;
    }

    // ---- prologue: stage tile t0's J-strip ----
    float4 ja, jb;
    float  s = 0.0f;
    {
        const unsigned j0  = (t0 & 31u) * 64u + rb;
        const float4*  src = (const float4*)(emb + j0 * 32u);
        ja = src[lane];
        jb = src[lane + 64u];
        if (lane < CHUNK_ROWS) s = sw[j0 + lane];
    }
    {
        float* dA = my + jrA * ROWF + 32u + cc;
        dA[0] = ja.x; dA[1] = ja.y; dA[2] = ja.z; dA[3] = ja.w;
        float* dB = my + jrB * ROWF + 32u + cc;
        dB[0] = jb.x; dB[1] = jb.y; dB[2] = jb.z; dB[3] = jb.w;
        if (lane < CHUNK_ROWS) my[lane * ROWF + 64u] = s;
    }

#pragma unroll 1
    for (unsigned kk = 0; kk < TILES_PER_BLOCK; ++kk) {
        const unsigned tile = t0 + kk;

        // prefetch next tile's J-strip into registers (L2-hot, latency hides
        // under this tile's drain; no barrier -> compiler uses counted vmcnt)
        if (kk + 1u < TILES_PER_BLOCK) {
            const unsigned j0  = ((tile + 1u) & 31u) * 64u + rb;
            const float4*  src = (const float4*)(emb + j0 * 32u);
            ja = src[lane];
            jb = src[lane + 64u];
            if (lane < CHUNK_ROWS) s = sw[j0 + lane];
        }

        // ensure prior iteration's LDS writes are retired before reading
        asm volatile("s_waitcnt lgkmcnt(0)" ::: "memory");
        __builtin_amdgcn_sched_barrier(0);

        // drain: 260 f4 = 16x65 image, aligned b128 reads
        const float4* __restrict__ b4 = (const float4*)my;
        float4 r0 = b4[lane];
        float4 r1 = b4[lane + 64u];
        float4 r2 = b4[lane + 128u];
        float4 r3 = b4[lane + 192u];
        float4 r4 = {0.f, 0.f, 0.f, 0.f};
        if (lane < 4u) r4 = b4[lane + 256u];

        // reads must be complete before next writes (cross-lane WAR) — this
        // wait is free: the stores below need the read data anyway.
        asm volatile("s_waitcnt lgkmcnt(0)" ::: "memory");
        __builtin_amdgcn_sched_barrier(0);

        const unsigned base = tile * 1040u + w * 260u;   // f4 units, <2^27
        out[base + lane]        = r0;
        out[base + lane + 64u]  = r1;
        out[base + lane + 128u] = r2;
        out[base + lane + 192u] = r3;
        if (lane < 4u) out[base + lane + 256u] = r4;

        // scalar-write next tile's J-strip (stores above already hold their
        // data in registers; these ds_writes overlap with store issue)
        if (kk + 1u < TILES_PER_BLOCK) {
            float* dA = my + jrA * ROWF + 32u + cc;
            dA[0] = ja.x; dA[1] = ja.y; dA[2] = ja.z; dA[3] = ja.w;
            float* dB = my + jrB * ROWF + 32u + cc;
            dB[0] = jb.x; dB[1] = jb.y; dB[2] = jb.z; dB[3] = jb.w;
            if (lane < CHUNK_ROWS) my[lane * ROWF + 64u] = s;
        }
        __builtin_amdgcn_sched_barrier(0);
    }
}

extern "C" void kernel_launch(void* const* d_in, const int* in_sizes, int n_in,
                              void* d_out, int out_size, void* d_ws, size_t ws_size,
                              hipStream_t stream) {
    const float* emb = (const float*)d_in[0];   // [2048, 32] f32
    const float* sw  = (const float*)d_in[1];   // [2048] f32
    float4* out      = (float4*)d_out;

    expand_wavesync<<<dim3(NBLOCKS), dim3(256), 0, stream>>>(emb, sw, out);
}